// Round 13
// baseline (19.263 us; speedup 1.0000x reference)
//
#include <hip/hip_runtime.h>
#include <hip/hip_bf16.h>
#include <math.h>

// QuantumBottle, fused single kernel; phase D on the MATRIX CORE.
// out[b][j] = bias_j + sum_{m<81} E[b][m] * G[j][m],
//   E[b] = e01 (x) e23 basis from theta_w = tanh(z_w)*scale,
//   G    = 81x4 coefficient table built per block (phases A-C).
// R13 vs R12: (1) all 4 z float4 loads issued at KERNEL ENTRY -> HBM latency
// hidden under setup phases; (2) MFMA accumulation split into independent
// accH/accL chains (3-deep each instead of one 6-deep chain).

typedef __attribute__((ext_vector_type(8))) short bf16x8;
typedef __attribute__((ext_vector_type(4))) float f32x4;

__device__ __forceinline__ float2 qb_cmul(float2 a, float2 b) {
    return make_float2(a.x * b.x - a.y * b.y, a.x * b.y + a.y * b.x);
}

__device__ __forceinline__ unsigned qb_pk(float a, float b) {
    union { __hip_bfloat16 h; unsigned short u; } A, B;
    A.h = __float2bfloat16(a);
    B.h = __float2bfloat16(b);
    return (unsigned)A.u | ((unsigned)B.u << 16);
}

__global__ void __launch_bounds__(256) qb_fused(
    const float* __restrict__ z, const float* __restrict__ scale,
    const float* __restrict__ qw, const float* __restrict__ W,
    const float* __restrict__ bias, float* __restrict__ out, int Bn)
{
    // LDS pool: setup tables (10688 B) overlaid by phase-D E panels (53248 B).
    __shared__ __align__(16) char shpool[53248];
    __shared__ __align__(16) float sC[81 * 4];
    __shared__ __align__(16) unsigned short sGbH[4][96];
    __shared__ __align__(16) unsigned short sGbL[4][96];

    float  (*sTrig)[6]  = (float(*)[6])  (shpool);          // 192 B
    float2  *sU         = (float2*)      (shpool + 192);    // 256 B
    float2 (*sV1)[16]   = (float2(*)[16])(shpool + 448);    // 2048 B
    float2 (*sU2)[16]   = (float2(*)[16])(shpool + 2496);   // 2048 B
    float  (*Vr)[16]    = (float(*)[16]) (shpool + 4544);   // 1024 B
    float  (*Vi)[16]    = (float(*)[16]) (shpool + 5568);   // 1024 B
    float4  *sM         = (float4*)      (shpool + 6592);   // 4096 B -> 10688
    unsigned short *Eb  = (unsigned short*)shpool;          // phase D: [4][64][104]

    const int tid = threadIdx.x;
    const int lane = tid & 63, wid = tid >> 6;
    const int base = blockIdx.x * 1024 + wid * 256;

    // ---- prefetch all 4 z-vectors NOW; latency hides under setup ----
    const float4 zzero = make_float4(0.f, 0.f, 0.f, 0.f);
    const int i0_ = base + 0 * 64 + lane, i1_ = base + 1 * 64 + lane;
    const int i2_ = base + 2 * 64 + lane, i3_ = base + 3 * 64 + lane;
    const float4 zp0 = (i0_ < Bn) ? reinterpret_cast<const float4*>(z)[i0_] : zzero;
    const float4 zp1 = (i1_ < Bn) ? reinterpret_cast<const float4*>(z)[i1_] : zzero;
    const float4 zp2 = (i2_ < Bn) ? reinterpret_cast<const float4*>(z)[i2_] : zzero;
    const float4 zp3 = (i3_ < Bn) ? reinterpret_cast<const float4*>(z)[i3_] : zzero;

    // ---- A1: trig table (24 threads) ----
    if (tid < 24) {
        const int g = tid / 3, which = tid % 3;
        const float phi = qw[g * 3 + 0], th = qw[g * 3 + 1], om = qw[g * 3 + 2];
        const float ang = (which == 0) ? 0.5f * th
                        : (which == 1) ? 0.5f * (phi + om)
                                       : 0.5f * (phi - om);
        float sn, cs;
        __sincosf(ang, &sn, &cs);
        sTrig[g][2 * which + 0] = cs;
        sTrig[g][2 * which + 1] = sn;
    }
    __syncthreads();

    // ---- A2a: 2x2 Rot gate entries (32 threads) ----
    if (tid < 32) {
        const int l = tid >> 4, w = (tid >> 2) & 3, r = (tid >> 1) & 1, c = tid & 1;
        const int g = l * 4 + w;
        const float ct  = sTrig[g][0], st  = sTrig[g][1];
        const float epr = sTrig[g][2], epi = -sTrig[g][3];
        const float emr = sTrig[g][4], emi = -sTrig[g][5];
        float re, im;
        if (r == 0 && c == 0)      { re =  epr * ct; im =  epi * ct; }
        else if (r == 0)           { re = -emr * st; im =  emi * st; }
        else if (c == 0)           { re =  emr * st; im =  emi * st; }
        else                       { re =  epr * ct; im = -epi * ct; }
        sU[((l * 4 + w) * 2 + r) * 2 + c] = make_float2(re, im);
    }
    __syncthreads();

    // ---- A2b: tensor-product entries for both layers (256 threads) ----
    const int vi = tid >> 4, vk = tid & 15;
    {
        const int i0 = (vi >> 3) & 1, i1 = (vi >> 2) & 1, i2 = (vi >> 1) & 1, i3 = vi & 1;
        const int k0 = (vk >> 3) & 1, k1 = (vk >> 2) & 1, k2 = (vk >> 1) & 1, k3 = vk & 1;
        int b0 = i0, b1 = i1, b2 = i2, b3 = i3;
        b1 ^= b0; b2 ^= b1; b3 ^= b2; b0 ^= b3;          // CNOT-ring permutation
        const int sig = (b0 << 3) | (b1 << 2) | (b2 << 1) | b3;
        const float2 e1 = qb_cmul(qb_cmul(sU[(0*4+0)*4 + i0*2 + k0], sU[(0*4+1)*4 + i1*2 + k1]),
                                  qb_cmul(sU[(0*4+2)*4 + i2*2 + k2], sU[(0*4+3)*4 + i3*2 + k3]));
        const float2 e2 = qb_cmul(qb_cmul(sU[(1*4+0)*4 + i0*2 + k0], sU[(1*4+1)*4 + i1*2 + k1]),
                                  qb_cmul(sU[(1*4+2)*4 + i2*2 + k2], sU[(1*4+3)*4 + i3*2 + k3]));
        sV1[sig][vk] = e1;
        sU2[vi][vk]  = e2;
    }
    __syncthreads();

    // ---- A2c: V = P * U2 * V1 (16x16 complex matmul, 256 threads) ----
    {
        const int i0 = (vi >> 3) & 1, i1 = (vi >> 2) & 1, i2 = (vi >> 1) & 1, i3 = vi & 1;
        int b0 = i0, b1 = i1, b2 = i2, b3 = i3;
        b1 ^= b0; b2 ^= b1; b3 ^= b2; b0 ^= b3;
        const int sig = (b0 << 3) | (b1 << 2) | (b2 << 1) | b3;
        float accr = 0.f, acci = 0.f;
        #pragma unroll
        for (int m = 0; m < 16; ++m) {
            const float2 u = sU2[vi][m];
            const float2 v = sV1[m][vk];
            accr += u.x * v.x - u.y * v.y;
            acci += u.x * v.y + u.y * v.x;
        }
        Vr[sig][vk] = accr;
        Vi[sig][vk] = acci;
    }
    __syncthreads();

    // ---- B: M_w[k,kp] (256 threads) ----
    {
        const int k = tid >> 4, kp = tid & 15;
        float m0 = 0.f, m1 = 0.f, m2 = 0.f, m3 = 0.f;
        #pragma unroll
        for (int i = 0; i < 16; ++i) {
            const float pr = Vr[i][k] * Vr[i][kp] + Vi[i][k] * Vi[i][kp];
            m0 += ((i >> 3) & 1) ? -pr : pr;
            m1 += ((i >> 2) & 1) ? -pr : pr;
            m2 += ((i >> 1) & 1) ? -pr : pr;
            m3 += ( i       & 1) ? -pr : pr;
        }
        sM[tid] = make_float4(m0, m1, m2, m3);
    }
    __syncthreads();

    // ---- C: G_j[m] over the 3^4 basis (81 threads) ----
    if (tid < 81) {
        const int mm[4] = { tid / 27, (tid / 9) % 3, (tid / 3) % 3, tid % 3 };
        float h0 = 0.f, h1 = 0.f, h2 = 0.f, h3 = 0.f;
        #pragma unroll
        for (int t16 = 0; t16 < 16; ++t16) {
            int k = 0, kp = 0;
            float sgn = 0.0625f;
            #pragma unroll
            for (int w = 0; w < 4; ++w) {
                const int b = (t16 >> (3 - w)) & 1;
                int kw, kpw;
                if (mm[w] == 2) { kw = b; kpw = 1 - b; }
                else            { kw = b; kpw = b; if (mm[w] == 1 && b) sgn = -sgn; }
                k  |= kw  << (3 - w);
                kp |= kpw << (3 - w);
            }
            const float4 mv = sM[k * 16 + kp];
            h0 += sgn * mv.x; h1 += sgn * mv.y; h2 += sgn * mv.z; h3 += sgn * mv.w;
        }
        #pragma unroll
        for (int j = 0; j < 4; ++j) {
            sC[tid * 4 + j] = W[j * 4 + 0] * h0 + W[j * 4 + 1] * h1 +
                              W[j * 4 + 2] * h2 + W[j * 4 + 3] * h3;
        }
    }
    __syncthreads();

    // ---- C2: bf16 hi/lo split G tables, K padded to 96 (96 threads) ----
    if (tid < 96) {
        #pragma unroll
        for (int j = 0; j < 4; ++j) {
            float gv = (tid < 81) ? sC[tid * 4 + j] : 0.0f;
            union { __hip_bfloat16 h; unsigned short u; } H, L;
            H.h = __float2bfloat16(gv);
            float hi = __bfloat162float(H.h);
            L.h = __float2bfloat16(gv - hi);
            sGbH[j][tid] = H.u;
            sGbL[j][tid] = L.u;
        }
    }
    __syncthreads();   // also orders all setup-table reads before Eb overwrites

    // ---- D: MFMA multilinear evaluation ----
    const int fm = lane & 15, koct = lane >> 4;

    bf16x8 aH0 = {0,0,0,0,0,0,0,0}, aH1 = aH0, aH2 = aH0;
    bf16x8 aL0 = aH0, aL1 = aH0, aL2 = aH0;
    if (fm < 4) {
        aH0 = *reinterpret_cast<const bf16x8*>(&sGbH[fm][ 0 + koct * 8]);
        aH1 = *reinterpret_cast<const bf16x8*>(&sGbH[fm][32 + koct * 8]);
        aH2 = *reinterpret_cast<const bf16x8*>(&sGbH[fm][64 + koct * 8]);
        aL0 = *reinterpret_cast<const bf16x8*>(&sGbL[fm][ 0 + koct * 8]);
        aL1 = *reinterpret_cast<const bf16x8*>(&sGbL[fm][32 + koct * 8]);
        aL2 = *reinterpret_cast<const bf16x8*>(&sGbL[fm][64 + koct * 8]);
    }
    const float sc = scale[0];
    f32x4 biasv;
    biasv[0] = bias[0]; biasv[1] = bias[1]; biasv[2] = bias[2]; biasv[3] = bias[3];

    unsigned short* ebw = Eb + (wid * 64) * 104;       // wave-private panel

    auto dbody = [&](int s0, const float4& zv) {
        const float zz[4] = { zv.x, zv.y, zv.z, zv.w };
        float c[4], sn[4];
        #pragma unroll
        for (int w = 0; w < 4; ++w) {
            const float e = __expf(2.0f * zz[w]);
            const float t = 1.0f - __fdividef(2.0f, e + 1.0f);   // tanh
            __sincosf(t * sc, &sn[w], &c[w]);
        }
        const float e01[9] = { 1.0f,  c[1],        sn[1],
                               c[0],  c[0]*c[1],   c[0]*sn[1],
                               sn[0], sn[0]*c[1],  sn[0]*sn[1] };
        const float e23[9] = { 1.0f,  c[3],        sn[3],
                               c[2],  c[2]*c[3],   c[2]*sn[3],
                               sn[2], sn[2]*c[3],  sn[2]*sn[3] };

        uint4* rowv = reinterpret_cast<uint4*>(ebw + lane * 104);
        #pragma unroll
        for (int oct = 0; oct < 10; ++oct) {
            float E[8];
            #pragma unroll
            for (int e = 0; e < 8; ++e) {
                const int mm = oct * 8 + e;              // < 80, compile-time
                E[e] = e01[mm / 9] * e23[mm % 9];
            }
            rowv[oct] = make_uint4(qb_pk(E[0], E[1]), qb_pk(E[2], E[3]),
                                   qb_pk(E[4], E[5]), qb_pk(E[6], E[7]));
        }
        rowv[10] = make_uint4(qb_pk(e01[8] * e23[8], 0.f), 0u, 0u, 0u);  // m=80
        rowv[11] = make_uint4(0u, 0u, 0u, 0u);                            // pad

        #pragma unroll
        for (int p = 0; p < 4; ++p) {
            const unsigned short* br = ebw + (p * 16 + fm) * 104;
            const bf16x8 b0v = *reinterpret_cast<const bf16x8*>(br +  0 + koct * 8);
            const bf16x8 b1v = *reinterpret_cast<const bf16x8*>(br + 32 + koct * 8);
            const bf16x8 b2v = *reinterpret_cast<const bf16x8*>(br + 64 + koct * 8);
            // two independent 3-deep MFMA chains (H and L), merged at the end
            f32x4 accH = biasv;
            f32x4 accL; accL[0] = accL[1] = accL[2] = accL[3] = 0.0f;
            accH = __builtin_amdgcn_mfma_f32_16x16x32_bf16(aH0, b0v, accH, 0, 0, 0);
            accL = __builtin_amdgcn_mfma_f32_16x16x32_bf16(aL0, b0v, accL, 0, 0, 0);
            accH = __builtin_amdgcn_mfma_f32_16x16x32_bf16(aH1, b1v, accH, 0, 0, 0);
            accL = __builtin_amdgcn_mfma_f32_16x16x32_bf16(aL1, b1v, accL, 0, 0, 0);
            accH = __builtin_amdgcn_mfma_f32_16x16x32_bf16(aH2, b2v, accH, 0, 0, 0);
            accL = __builtin_amdgcn_mfma_f32_16x16x32_bf16(aL2, b2v, accL, 0, 0, 0);
            if (koct == 0) {
                const int oidx = s0 + p * 16 + lane;     // lane = fm < 16 here
                if (oidx < Bn)
                    reinterpret_cast<float4*>(out)[oidx] =
                        make_float4(accH[0] + accL[0], accH[1] + accL[1],
                                    accH[2] + accL[2], accH[3] + accL[3]);
            }
        }
    };

    dbody(base + 0 * 64, zp0);
    asm volatile("" ::: "memory");
    dbody(base + 1 * 64, zp1);
    asm volatile("" ::: "memory");
    dbody(base + 2 * 64, zp2);
    asm volatile("" ::: "memory");
    dbody(base + 3 * 64, zp3);
}

extern "C" void kernel_launch(void* const* d_in, const int* in_sizes, int n_in,
                              void* d_out, int out_size, void* d_ws, size_t ws_size,
                              hipStream_t stream) {
    const float* z  = (const float*)d_in[0];   // (B,4)
    const float* sc = (const float*)d_in[1];   // scalar
    const float* qw = (const float*)d_in[2];   // (2,4,3)
    const float* W  = (const float*)d_in[3];   // (4,4)
    const float* bb = (const float*)d_in[4];   // (4,)
    float* out = (float*)d_out;

    const int Bn = in_sizes[0] / 4;
    const int blocks = (Bn + 1023) / 1024;     // 1024 samples per block

    hipLaunchKernelGGL(qb_fused, dim3(blocks), dim3(256), 0, stream,
                       z, sc, qw, W, bb, out, Bn);
}

// Round 14
// 16.676 us; speedup vs baseline: 1.1551x; 1.1551x over previous
//
#include <hip/hip_runtime.h>
#include <hip/hip_bf16.h>
#include <math.h>

// QuantumBottle, fused single kernel; phase D on the MATRIX CORE.
// out[b][j] = bias_j + sum_{m<81} E[b][m] * G[j][m],
//   E[b] = e01 (x) e23 basis from theta_w = tanh(z_w)*scale,
//   G    = 81x4 coefficient table built per block (phases A-C).
// R14 vs R12: single bf16 G (no hi/lo split -> 3 MFMAs per pass, not 6).
// absmax has been pinned at 2^-8 (E's bf16 ulp) since R12 -> the lo-half
// contributed nothing measurable; threshold 0.0202 gives 5x headroom.
// Panel pad rows pre-zeroed once (10 b128 + 1 b32 writes/iter, was 12).
// R13's entry-prefetch + chain-split REGRESSED (17.3->19.3) -> reverted.

typedef __attribute__((ext_vector_type(8))) short bf16x8;
typedef __attribute__((ext_vector_type(4))) float f32x4;

__device__ __forceinline__ float2 qb_cmul(float2 a, float2 b) {
    return make_float2(a.x * b.x - a.y * b.y, a.x * b.y + a.y * b.x);
}

__device__ __forceinline__ unsigned qb_pk(float a, float b) {
    union { __hip_bfloat16 h; unsigned short u; } A, B;
    A.h = __float2bfloat16(a);
    B.h = __float2bfloat16(b);
    return (unsigned)A.u | ((unsigned)B.u << 16);
}

__global__ void __launch_bounds__(256) qb_fused(
    const float* __restrict__ z, const float* __restrict__ scale,
    const float* __restrict__ qw, const float* __restrict__ W,
    const float* __restrict__ bias, float* __restrict__ out, int Bn)
{
    // LDS pool: setup tables (10688 B) overlaid by phase-D E panels (53248 B).
    __shared__ __align__(16) char shpool[53248];
    __shared__ __align__(16) float sC[81 * 4];
    __shared__ __align__(16) unsigned short sGb[4][96];

    float  (*sTrig)[6]  = (float(*)[6])  (shpool);          // 192 B
    float2  *sU         = (float2*)      (shpool + 192);    // 256 B
    float2 (*sV1)[16]   = (float2(*)[16])(shpool + 448);    // 2048 B
    float2 (*sU2)[16]   = (float2(*)[16])(shpool + 2496);   // 2048 B
    float  (*Vr)[16]    = (float(*)[16]) (shpool + 4544);   // 1024 B
    float  (*Vi)[16]    = (float(*)[16]) (shpool + 5568);   // 1024 B
    float4  *sM         = (float4*)      (shpool + 6592);   // 4096 B -> 10688
    unsigned short *Eb  = (unsigned short*)shpool;          // phase D: [4][64][104]

    const int tid = threadIdx.x;

    // ---- A1: trig table (24 threads) ----
    if (tid < 24) {
        const int g = tid / 3, which = tid % 3;
        const float phi = qw[g * 3 + 0], th = qw[g * 3 + 1], om = qw[g * 3 + 2];
        const float ang = (which == 0) ? 0.5f * th
                        : (which == 1) ? 0.5f * (phi + om)
                                       : 0.5f * (phi - om);
        float sn, cs;
        __sincosf(ang, &sn, &cs);
        sTrig[g][2 * which + 0] = cs;
        sTrig[g][2 * which + 1] = sn;
    }
    __syncthreads();

    // ---- A2a: 2x2 Rot gate entries (32 threads) ----
    if (tid < 32) {
        const int l = tid >> 4, w = (tid >> 2) & 3, r = (tid >> 1) & 1, c = tid & 1;
        const int g = l * 4 + w;
        const float ct  = sTrig[g][0], st  = sTrig[g][1];
        const float epr = sTrig[g][2], epi = -sTrig[g][3];
        const float emr = sTrig[g][4], emi = -sTrig[g][5];
        float re, im;
        if (r == 0 && c == 0)      { re =  epr * ct; im =  epi * ct; }
        else if (r == 0)           { re = -emr * st; im =  emi * st; }
        else if (c == 0)           { re =  emr * st; im =  emi * st; }
        else                       { re =  epr * ct; im = -epi * ct; }
        sU[((l * 4 + w) * 2 + r) * 2 + c] = make_float2(re, im);
    }
    __syncthreads();

    // ---- A2b: tensor-product entries for both layers (256 threads) ----
    const int vi = tid >> 4, vk = tid & 15;
    {
        const int i0 = (vi >> 3) & 1, i1 = (vi >> 2) & 1, i2 = (vi >> 1) & 1, i3 = vi & 1;
        const int k0 = (vk >> 3) & 1, k1 = (vk >> 2) & 1, k2 = (vk >> 1) & 1, k3 = vk & 1;
        int b0 = i0, b1 = i1, b2 = i2, b3 = i3;
        b1 ^= b0; b2 ^= b1; b3 ^= b2; b0 ^= b3;          // CNOT-ring permutation
        const int sig = (b0 << 3) | (b1 << 2) | (b2 << 1) | b3;
        const float2 e1 = qb_cmul(qb_cmul(sU[(0*4+0)*4 + i0*2 + k0], sU[(0*4+1)*4 + i1*2 + k1]),
                                  qb_cmul(sU[(0*4+2)*4 + i2*2 + k2], sU[(0*4+3)*4 + i3*2 + k3]));
        const float2 e2 = qb_cmul(qb_cmul(sU[(1*4+0)*4 + i0*2 + k0], sU[(1*4+1)*4 + i1*2 + k1]),
                                  qb_cmul(sU[(1*4+2)*4 + i2*2 + k2], sU[(1*4+3)*4 + i3*2 + k3]));
        sV1[sig][vk] = e1;
        sU2[vi][vk]  = e2;
    }
    __syncthreads();

    // ---- A2c: V = P * U2 * V1 (16x16 complex matmul, 256 threads) ----
    {
        const int i0 = (vi >> 3) & 1, i1 = (vi >> 2) & 1, i2 = (vi >> 1) & 1, i3 = vi & 1;
        int b0 = i0, b1 = i1, b2 = i2, b3 = i3;
        b1 ^= b0; b2 ^= b1; b3 ^= b2; b0 ^= b3;
        const int sig = (b0 << 3) | (b1 << 2) | (b2 << 1) | b3;
        float accr = 0.f, acci = 0.f;
        #pragma unroll
        for (int m = 0; m < 16; ++m) {
            const float2 u = sU2[vi][m];
            const float2 v = sV1[m][vk];
            accr += u.x * v.x - u.y * v.y;
            acci += u.x * v.y + u.y * v.x;
        }
        Vr[sig][vk] = accr;
        Vi[sig][vk] = acci;
    }
    __syncthreads();

    // ---- B: M_w[k,kp] (256 threads) ----
    {
        const int k = tid >> 4, kp = tid & 15;
        float m0 = 0.f, m1 = 0.f, m2 = 0.f, m3 = 0.f;
        #pragma unroll
        for (int i = 0; i < 16; ++i) {
            const float pr = Vr[i][k] * Vr[i][kp] + Vi[i][k] * Vi[i][kp];
            m0 += ((i >> 3) & 1) ? -pr : pr;
            m1 += ((i >> 2) & 1) ? -pr : pr;
            m2 += ((i >> 1) & 1) ? -pr : pr;
            m3 += ( i       & 1) ? -pr : pr;
        }
        sM[tid] = make_float4(m0, m1, m2, m3);
    }
    __syncthreads();

    // ---- C: G_j[m] over the 3^4 basis (81 threads) ----
    if (tid < 81) {
        const int mm[4] = { tid / 27, (tid / 9) % 3, (tid / 3) % 3, tid % 3 };
        float h0 = 0.f, h1 = 0.f, h2 = 0.f, h3 = 0.f;
        #pragma unroll
        for (int t16 = 0; t16 < 16; ++t16) {
            int k = 0, kp = 0;
            float sgn = 0.0625f;
            #pragma unroll
            for (int w = 0; w < 4; ++w) {
                const int b = (t16 >> (3 - w)) & 1;
                int kw, kpw;
                if (mm[w] == 2) { kw = b; kpw = 1 - b; }
                else            { kw = b; kpw = b; if (mm[w] == 1 && b) sgn = -sgn; }
                k  |= kw  << (3 - w);
                kp |= kpw << (3 - w);
            }
            const float4 mv = sM[k * 16 + kp];
            h0 += sgn * mv.x; h1 += sgn * mv.y; h2 += sgn * mv.z; h3 += sgn * mv.w;
        }
        #pragma unroll
        for (int j = 0; j < 4; ++j) {
            sC[tid * 4 + j] = W[j * 4 + 0] * h0 + W[j * 4 + 1] * h1 +
                              W[j * 4 + 2] * h2 + W[j * 4 + 3] * h3;
        }
    }
    __syncthreads();

    // ---- C2: bf16 G table, K padded to 96 (96 threads) ----
    if (tid < 96) {
        #pragma unroll
        for (int j = 0; j < 4; ++j) {
            float gv = (tid < 81) ? sC[tid * 4 + j] : 0.0f;
            union { __hip_bfloat16 h; unsigned short u; } H;
            H.h = __float2bfloat16(gv);
            sGb[j][tid] = H.u;
        }
    }
    __syncthreads();   // also orders all setup-table reads before Eb overwrites

    // ---- D: MFMA multilinear evaluation ----
    const int lane = tid & 63, wid = tid >> 6;
    const int fm = lane & 15, koct = lane >> 4;

    bf16x8 aG0 = {0,0,0,0,0,0,0,0}, aG1 = aG0, aG2 = aG0;
    if (fm < 4) {
        aG0 = *reinterpret_cast<const bf16x8*>(&sGb[fm][ 0 + koct * 8]);
        aG1 = *reinterpret_cast<const bf16x8*>(&sGb[fm][32 + koct * 8]);
        aG2 = *reinterpret_cast<const bf16x8*>(&sGb[fm][64 + koct * 8]);
    }
    const float sc = scale[0];
    f32x4 biasv;
    biasv[0] = bias[0]; biasv[1] = bias[1]; biasv[2] = bias[2]; biasv[3] = bias[3];

    unsigned short* ebw = Eb + (wid * 64) * 104;       // wave-private panel
    const int base = blockIdx.x * 1024 + wid * 256;

    // pre-zero the constant pad region of this lane's row (shorts 81..103)
    {
        uint4* rowv = reinterpret_cast<uint4*>(ebw + lane * 104);
        *reinterpret_cast<uint2*>(ebw + lane * 104 + 84) = make_uint2(0u, 0u); // 84..87
        rowv[11] = make_uint4(0u, 0u, 0u, 0u);                                 // 88..95? no: shorts 88..103
        // shorts 81..83:
        ebw[lane * 104 + 81] = 0; ebw[lane * 104 + 82] = 0; ebw[lane * 104 + 83] = 0;
        // shorts 96..103 (pad to stride):
        rowv[12] = make_uint4(0u, 0u, 0u, 0u);
    }

    #pragma unroll 1
    for (int sp = 0; sp < 4; ++sp) {
        const int s0 = base + sp * 64;
        const int myIdx = s0 + lane;
        const float4 zv = (myIdx < Bn) ? reinterpret_cast<const float4*>(z)[myIdx]
                                       : make_float4(0.f, 0.f, 0.f, 0.f);
        const float zz[4] = { zv.x, zv.y, zv.z, zv.w };
        float c[4], sn[4];
        #pragma unroll
        for (int w = 0; w < 4; ++w) {
            const float e = __expf(2.0f * zz[w]);
            const float t = 1.0f - __fdividef(2.0f, e + 1.0f);   // tanh
            __sincosf(t * sc, &sn[w], &c[w]);
        }
        const float e01[9] = { 1.0f,  c[1],        sn[1],
                               c[0],  c[0]*c[1],   c[0]*sn[1],
                               sn[0], sn[0]*c[1],  sn[0]*sn[1] };
        const float e23[9] = { 1.0f,  c[3],        sn[3],
                               c[2],  c[2]*c[3],   c[2]*sn[3],
                               sn[2], sn[2]*c[3],  sn[2]*sn[3] };

        uint4* rowv = reinterpret_cast<uint4*>(ebw + lane * 104);
        #pragma unroll
        for (int oct = 0; oct < 10; ++oct) {
            float E[8];
            #pragma unroll
            for (int e = 0; e < 8; ++e) {
                const int mm = oct * 8 + e;              // < 80, compile-time
                E[e] = e01[mm / 9] * e23[mm % 9];
            }
            rowv[oct] = make_uint4(qb_pk(E[0], E[1]), qb_pk(E[2], E[3]),
                                   qb_pk(E[4], E[5]), qb_pk(E[6], E[7]));
        }
        // m=80 element (shorts 80 paired with pre-zeroed 81)
        *reinterpret_cast<unsigned*>(ebw + lane * 104 + 80) = qb_pk(e01[8] * e23[8], 0.f);

        #pragma unroll
        for (int p = 0; p < 4; ++p) {
            const unsigned short* br = ebw + (p * 16 + fm) * 104;
            const bf16x8 b0v = *reinterpret_cast<const bf16x8*>(br +  0 + koct * 8);
            const bf16x8 b1v = *reinterpret_cast<const bf16x8*>(br + 32 + koct * 8);
            const bf16x8 b2v = *reinterpret_cast<const bf16x8*>(br + 64 + koct * 8);
            f32x4 acc = biasv;
            acc = __builtin_amdgcn_mfma_f32_16x16x32_bf16(aG0, b0v, acc, 0, 0, 0);
            acc = __builtin_amdgcn_mfma_f32_16x16x32_bf16(aG1, b1v, acc, 0, 0, 0);
            acc = __builtin_amdgcn_mfma_f32_16x16x32_bf16(aG2, b2v, acc, 0, 0, 0);
            if (koct == 0) {
                const int oidx = s0 + p * 16 + lane;     // lane = fm < 16 here
                if (oidx < Bn)
                    reinterpret_cast<float4*>(out)[oidx] =
                        make_float4(acc[0], acc[1], acc[2], acc[3]);
            }
        }
        asm volatile("" ::: "memory");
    }
}

extern "C" void kernel_launch(void* const* d_in, const int* in_sizes, int n_in,
                              void* d_out, int out_size, void* d_ws, size_t ws_size,
                              hipStream_t stream) {
    const float* z  = (const float*)d_in[0];   // (B,4)
    const float* sc = (const float*)d_in[1];   // scalar
    const float* qw = (const float*)d_in[2];   // (2,4,3)
    const float* W  = (const float*)d_in[3];   // (4,4)
    const float* bb = (const float*)d_in[4];   // (4,)
    float* out = (float*)d_out;

    const int Bn = in_sizes[0] / 4;
    const int blocks = (Bn + 1023) / 1024;     // 1024 samples per block

    hipLaunchKernelGGL(qb_fused, dim3(blocks), dim3(256), 0, stream,
                       z, sc, qw, W, bb, out, Bn);
}